// Round 1
// baseline (2016.214 us; speedup 1.0000x reference)
//
#include <hip/hip_runtime.h>
#include <hip/hip_bf16.h>

// Problem: B=4, T=2048, C=1024, H=16, HS=64. M = B*T = 8192.
#define B_ 4
#define T_ 2048
#define C_ 1024
#define H_ 16
#define HS_ 64
#define M_ (B_*T_)

typedef __bf16 bf16_t;
typedef bf16_t bf16x8 __attribute__((ext_vector_type(8)));
typedef float f32x4 __attribute__((ext_vector_type(4)));

__device__ __forceinline__ float bf2f(unsigned short u) {
    union { unsigned int i; float f; } x; x.i = ((unsigned int)u) << 16; return x.f;
}
__device__ __forceinline__ unsigned short f2bf(float f) {
    __hip_bfloat16 h = __float2bfloat16(f);
    return __builtin_bit_cast(unsigned short, h);
}

// ---------------- QKV GEMM: x[8192,1024] @ w_attn[1024,3072] + b ----------------
// Writes Q,K,V as bf16 in [B,H,T,HS] layout. Tile 128x64, BK=32, 4 waves (2x2).
__launch_bounds__(256)
__global__ void qkv_gemm(const float* __restrict__ x, const float* __restrict__ w,
                         const float* __restrict__ bias,
                         unsigned short* __restrict__ qw, unsigned short* __restrict__ kw,
                         unsigned short* __restrict__ vw) {
    const int N = 3 * C_;   // 3072
    const int K = C_;       // 1024
    __shared__ unsigned short As[128][40];  // +8 pad: b128 frag reads ~2-way (free)
    __shared__ unsigned short Bs[64][40];   // stored [n][k]
    const int tid = threadIdx.x;
    const int lane = tid & 63;
    const int wid = tid >> 6;
    const int waveM = wid >> 1, waveN = wid & 1;
    const int m0 = blockIdx.y * 128;
    const int n0 = blockIdx.x * 64;

    f32x4 acc[4][2];
    #pragma unroll
    for (int i = 0; i < 4; i++)
        #pragma unroll
        for (int j = 0; j < 2; j++) acc[i][j] = (f32x4)0.0f;

    for (int kk = 0; kk < K; kk += 32) {
        // stage A: 128x32 fp32 -> bf16 (coalesced float4 along k)
        #pragma unroll
        for (int i = 0; i < 4; i++) {
            int idx = tid + i * 256;            // 0..1023
            int row = idx >> 3, c4 = idx & 7;
            const float4 v = *(const float4*)&x[(size_t)(m0 + row) * K + kk + c4 * 4];
            ushort4 o; o.x = f2bf(v.x); o.y = f2bf(v.y); o.z = f2bf(v.z); o.w = f2bf(v.w);
            *(ushort4*)&As[row][c4 * 4] = o;
        }
        // stage B transposed: w is [K][N] row-major; LDS holds [n][k]
        #pragma unroll
        for (int i = 0; i < 2; i++) {
            int idx = tid + i * 256;            // 0..511
            int n = idx & 63, k4 = idx >> 6;    // k4: 0..7
            ushort4 o;
            o.x = f2bf(w[(size_t)(kk + k4 * 4 + 0) * N + n0 + n]);
            o.y = f2bf(w[(size_t)(kk + k4 * 4 + 1) * N + n0 + n]);
            o.z = f2bf(w[(size_t)(kk + k4 * 4 + 2) * N + n0 + n]);
            o.w = f2bf(w[(size_t)(kk + k4 * 4 + 3) * N + n0 + n]);
            *(ushort4*)&Bs[n][k4 * 4] = o;
        }
        __syncthreads();
        bf16x8 a[4], b[2];
        #pragma unroll
        for (int mf = 0; mf < 4; mf++)
            a[mf] = *(bf16x8*)&As[waveM * 64 + mf * 16 + (lane & 15)][8 * (lane >> 4)];
        #pragma unroll
        for (int nf = 0; nf < 2; nf++)
            b[nf] = *(bf16x8*)&Bs[waveN * 32 + nf * 16 + (lane & 15)][8 * (lane >> 4)];
        #pragma unroll
        for (int mf = 0; mf < 4; mf++)
            #pragma unroll
            for (int nf = 0; nf < 2; nf++)
                acc[mf][nf] = __builtin_amdgcn_mfma_f32_16x16x32_bf16(a[mf], b[nf], acc[mf][nf], 0, 0, 0);
        __syncthreads();
    }
    // epilogue: C/D layout col=lane&15, row=(lane>>4)*4+r (m89-verified)
    #pragma unroll
    for (int mf = 0; mf < 4; mf++)
        #pragma unroll
        for (int nf = 0; nf < 2; nf++)
            #pragma unroll
            for (int r = 0; r < 4; r++) {
                int rg = m0 + waveM * 64 + mf * 16 + (lane >> 4) * 4 + r;
                int cg = n0 + waveN * 32 + nf * 16 + (lane & 15);
                float val = acc[mf][nf][r] + bias[cg];
                int sec = cg >> 10;          // 0=q 1=k 2=v (block is within one section)
                int cc = cg & 1023;
                int h = cc >> 6, hs = cc & 63;
                int bb = rg >> 11, t = rg & 2047;
                unsigned short* dst = (sec == 0) ? qw : (sec == 1) ? kw : vw;
                dst[(((size_t)(bb * H_ + h)) * T_ + t) * HS_ + hs] = f2bf(val);
            }
}

// ---------------- Flash attention: 1 wave per query row (HS=64==wave) ----------------
__launch_bounds__(256)
__global__ void attn(const unsigned short* __restrict__ qw, const unsigned short* __restrict__ kw,
                     const unsigned short* __restrict__ vw, unsigned short* __restrict__ yw) {
    __shared__ unsigned short Ks[64][68];   // +4 pad -> 8B-aligned rows, small conflicts
    __shared__ unsigned short Vs[64][68];
    __shared__ float q_s[4][64];
    __shared__ float p_s[4][64];
    const int tid = threadIdx.x, lane = tid & 63, wid = tid >> 6;
    const int bh = blockIdx.x >> 9;             // / (T/4 = 512)
    const int t0 = (blockIdx.x & 511) * 4;
    const int t = t0 + wid;                     // this wave's query row
    const size_t base = (size_t)bh * T_ * HS_;

    q_s[wid][lane] = bf2f(qw[base + (size_t)t * HS_ + lane]) * 0.125f;  // 1/sqrt(64)
    float m = -INFINITY, l = 0.f, o = 0.f;
    const int ntiles = (t0 + 3) / 64 + 1;
    for (int kt = 0; kt < ntiles; kt++) {
        __syncthreads();
        #pragma unroll
        for (int i = 0; i < 4; i++) {
            int idx = tid + i * 256;            // 0..1023
            int row = idx >> 4, c4 = idx & 15;
            *(ushort4*)&Ks[row][c4 * 4] =
                *(const ushort4*)&kw[base + (size_t)(kt * 64 + row) * HS_ + c4 * 4];
            *(ushort4*)&Vs[row][c4 * 4] =
                *(const ushort4*)&vw[base + (size_t)(kt * 64 + row) * HS_ + c4 * 4];
        }
        __syncthreads();
        if (kt * 64 <= t) {
            // score for key j = lane
            float s = 0.f;
            #pragma unroll
            for (int d4 = 0; d4 < 16; d4++) {
                ushort4 k4v = *(ushort4*)&Ks[lane][d4 * 4];
                s += q_s[wid][d4 * 4 + 0] * bf2f(k4v.x);
                s += q_s[wid][d4 * 4 + 1] * bf2f(k4v.y);
                s += q_s[wid][d4 * 4 + 2] * bf2f(k4v.z);
                s += q_s[wid][d4 * 4 + 3] * bf2f(k4v.w);
            }
            int kj = kt * 64 + lane;
            if (kj > t) s = -INFINITY;
            float smax = s;
            #pragma unroll
            for (int off = 32; off >= 1; off >>= 1) smax = fmaxf(smax, __shfl_xor(smax, off));
            float mn = fmaxf(m, smax);
            float alpha = __expf(m - mn);       // m=-inf first tile -> 0
            float p = __expf(s - mn);           // masked -> 0
            float ps = p;
            #pragma unroll
            for (int off = 32; off >= 1; off >>= 1) ps += __shfl_xor(ps, off);
            l = l * alpha + ps;
            m = mn;
            o *= alpha;
            p_s[wid][lane] = p;                 // wave-synchronous LDS use
            #pragma unroll
            for (int j4 = 0; j4 < 16; j4++) {
                float4 pv = *(float4*)&p_s[wid][j4 * 4];  // uniform -> broadcast
                o += pv.x * bf2f(Vs[j4 * 4 + 0][lane]);
                o += pv.y * bf2f(Vs[j4 * 4 + 1][lane]);
                o += pv.z * bf2f(Vs[j4 * 4 + 2][lane]);
                o += pv.w * bf2f(Vs[j4 * 4 + 3][lane]);
            }
        }
    }
    const int bq = bh >> 4, h = bh & 15;
    yw[((size_t)(bq * T_ + t)) * C_ + h * HS_ + lane] = f2bf(o / l);
}

// ---------------- Output projection: y[8192,1024] @ w_proj[1024,1024] + b ----------------
__launch_bounds__(256)
__global__ void proj_gemm(const unsigned short* __restrict__ y, const float* __restrict__ w,
                          const float* __restrict__ bias, float* __restrict__ out) {
    const int N = C_, K = C_;
    __shared__ unsigned short As[128][40];
    __shared__ unsigned short Bs[64][40];
    const int tid = threadIdx.x;
    const int lane = tid & 63;
    const int wid = tid >> 6;
    const int waveM = wid >> 1, waveN = wid & 1;
    const int m0 = blockIdx.y * 128;
    const int n0 = blockIdx.x * 64;

    f32x4 acc[4][2];
    #pragma unroll
    for (int i = 0; i < 4; i++)
        #pragma unroll
        for (int j = 0; j < 2; j++) acc[i][j] = (f32x4)0.0f;

    for (int kk = 0; kk < K; kk += 32) {
        #pragma unroll
        for (int i = 0; i < 4; i++) {       // A already bf16: straight copy
            int idx = tid + i * 256;
            int row = idx >> 3, c4 = idx & 7;
            *(ushort4*)&As[row][c4 * 4] = *(const ushort4*)&y[(size_t)(m0 + row) * K + kk + c4 * 4];
        }
        #pragma unroll
        for (int i = 0; i < 2; i++) {
            int idx = tid + i * 256;
            int n = idx & 63, k4 = idx >> 6;
            ushort4 o;
            o.x = f2bf(w[(size_t)(kk + k4 * 4 + 0) * N + n0 + n]);
            o.y = f2bf(w[(size_t)(kk + k4 * 4 + 1) * N + n0 + n]);
            o.z = f2bf(w[(size_t)(kk + k4 * 4 + 2) * N + n0 + n]);
            o.w = f2bf(w[(size_t)(kk + k4 * 4 + 3) * N + n0 + n]);
            *(ushort4*)&Bs[n][k4 * 4] = o;
        }
        __syncthreads();
        bf16x8 a[4], b[2];
        #pragma unroll
        for (int mf = 0; mf < 4; mf++)
            a[mf] = *(bf16x8*)&As[waveM * 64 + mf * 16 + (lane & 15)][8 * (lane >> 4)];
        #pragma unroll
        for (int nf = 0; nf < 2; nf++)
            b[nf] = *(bf16x8*)&Bs[waveN * 32 + nf * 16 + (lane & 15)][8 * (lane >> 4)];
        #pragma unroll
        for (int mf = 0; mf < 4; mf++)
            #pragma unroll
            for (int nf = 0; nf < 2; nf++)
                acc[mf][nf] = __builtin_amdgcn_mfma_f32_16x16x32_bf16(a[mf], b[nf], acc[mf][nf], 0, 0, 0);
        __syncthreads();
    }
    #pragma unroll
    for (int mf = 0; mf < 4; mf++)
        #pragma unroll
        for (int nf = 0; nf < 2; nf++)
            #pragma unroll
            for (int r = 0; r < 4; r++) {
                int rg = m0 + waveM * 64 + mf * 16 + (lane >> 4) * 4 + r;
                int cg = n0 + waveN * 32 + nf * 16 + (lane & 15);
                out[(size_t)rg * N + cg] = acc[mf][nf][r] + bias[cg];
            }
}

extern "C" void kernel_launch(void* const* d_in, const int* in_sizes, int n_in,
                              void* d_out, int out_size, void* d_ws, size_t ws_size,
                              hipStream_t stream) {
    const float* x      = (const float*)d_in[0];
    const float* w_attn = (const float*)d_in[1];
    const float* b_attn = (const float*)d_in[2];
    const float* w_proj = (const float*)d_in[3];
    const float* b_proj = (const float*)d_in[4];
    float* out = (float*)d_out;

    // workspace layout (bf16): q,k,v in [B,H,T,HS]; y in [B,T,C].  4 * 16.8MB = 67MB
    unsigned short* qw = (unsigned short*)d_ws;
    const size_t E = (size_t)M_ * C_;   // 8388608
    unsigned short* kw = qw + E;
    unsigned short* vw = kw + E;
    unsigned short* yw = vw + E;

    qkv_gemm<<<dim3(48, 64), 256, 0, stream>>>(x, w_attn, b_attn, qw, kw, vw);
    attn<<<dim3(32768), 256, 0, stream>>>(qw, kw, vw, yw);
    proj_gemm<<<dim3(16, 64), 256, 0, stream>>>(yw, w_proj, b_proj, out);
}

// Round 3
// 545.966 us; speedup vs baseline: 3.6929x; 3.6929x over previous
//
#include <hip/hip_runtime.h>
#include <hip/hip_bf16.h>

// Problem: B=4, T=2048, C=1024, H=16, HS=64. M = B*T = 8192.
#define B_ 4
#define T_ 2048
#define C_ 1024
#define H_ 16
#define HS_ 64
#define M_ (B_*T_)

typedef __bf16 bf16_t;
typedef bf16_t bf16x8 __attribute__((ext_vector_type(8)));
typedef float f32x4 __attribute__((ext_vector_type(4)));

__device__ __forceinline__ float bf2f(unsigned short u) {
    union { unsigned int i; float f; } x; x.i = ((unsigned int)u) << 16; return x.f;
}
__device__ __forceinline__ unsigned short f2bf(float f) {
    __hip_bfloat16 h = __float2bfloat16(f);
    return __builtin_bit_cast(unsigned short, h);
}

// ---------------- QKV GEMM: x[8192,1024] @ w_attn[1024,3072] + b ----------------
// Q,K -> [B,H,T,HS] bf16.  V -> TRANSPOSED [B,H,HS,T] bf16 (for PV B-frags).
__launch_bounds__(256)
__global__ void qkv_gemm(const float* __restrict__ x, const float* __restrict__ w,
                         const float* __restrict__ bias,
                         unsigned short* __restrict__ qw, unsigned short* __restrict__ kw,
                         unsigned short* __restrict__ vt) {
    const int N = 3 * C_;   // 3072
    const int K = C_;       // 1024
    __shared__ unsigned short As[128][40];
    __shared__ unsigned short Bs[64][40];
    const int tid = threadIdx.x;
    const int lane = tid & 63;
    const int wid = tid >> 6;
    const int waveM = wid >> 1, waveN = wid & 1;
    const int m0 = blockIdx.y * 128;
    const int n0 = blockIdx.x * 64;

    f32x4 acc[4][2];
    #pragma unroll
    for (int i = 0; i < 4; i++)
        #pragma unroll
        for (int j = 0; j < 2; j++) acc[i][j] = (f32x4)0.0f;

    for (int kk = 0; kk < K; kk += 32) {
        #pragma unroll
        for (int i = 0; i < 4; i++) {
            int idx = tid + i * 256;
            int row = idx >> 3, c4 = idx & 7;
            const float4 v = *(const float4*)&x[(size_t)(m0 + row) * K + kk + c4 * 4];
            ushort4 o; o.x = f2bf(v.x); o.y = f2bf(v.y); o.z = f2bf(v.z); o.w = f2bf(v.w);
            *(ushort4*)&As[row][c4 * 4] = o;
        }
        #pragma unroll
        for (int i = 0; i < 2; i++) {
            int idx = tid + i * 256;
            int n = idx & 63, k4 = idx >> 6;
            ushort4 o;
            o.x = f2bf(w[(size_t)(kk + k4 * 4 + 0) * N + n0 + n]);
            o.y = f2bf(w[(size_t)(kk + k4 * 4 + 1) * N + n0 + n]);
            o.z = f2bf(w[(size_t)(kk + k4 * 4 + 2) * N + n0 + n]);
            o.w = f2bf(w[(size_t)(kk + k4 * 4 + 3) * N + n0 + n]);
            *(ushort4*)&Bs[n][k4 * 4] = o;
        }
        __syncthreads();
        bf16x8 a[4], b[2];
        #pragma unroll
        for (int mf = 0; mf < 4; mf++)
            a[mf] = *(bf16x8*)&As[waveM * 64 + mf * 16 + (lane & 15)][8 * (lane >> 4)];
        #pragma unroll
        for (int nf = 0; nf < 2; nf++)
            b[nf] = *(bf16x8*)&Bs[waveN * 32 + nf * 16 + (lane & 15)][8 * (lane >> 4)];
        #pragma unroll
        for (int mf = 0; mf < 4; mf++)
            #pragma unroll
            for (int nf = 0; nf < 2; nf++)
                acc[mf][nf] = __builtin_amdgcn_mfma_f32_16x16x32_bf16(a[mf], b[nf], acc[mf][nf], 0, 0, 0);
        __syncthreads();
    }
    #pragma unroll
    for (int mf = 0; mf < 4; mf++)
        #pragma unroll
        for (int nf = 0; nf < 2; nf++)
            #pragma unroll
            for (int r = 0; r < 4; r++) {
                int rg = m0 + waveM * 64 + mf * 16 + (lane >> 4) * 4 + r;
                int cg = n0 + waveN * 32 + nf * 16 + (lane & 15);
                float val = acc[mf][nf][r] + bias[cg];
                int sec = cg >> 10;          // 0=q 1=k 2=v
                int cc = cg & 1023;
                int h = cc >> 6, hs = cc & 63;
                int bb = rg >> 11, t = rg & 2047;
                if (sec == 0)
                    qw[(((size_t)(bb * H_ + h)) * T_ + t) * HS_ + hs] = f2bf(val);
                else if (sec == 1)
                    kw[(((size_t)(bb * H_ + h)) * T_ + t) * HS_ + hs] = f2bf(val);
                else
                    vt[(((size_t)(bb * H_ + h)) * HS_ + hs) * T_ + t] = f2bf(val);
            }
}

// ---------------- MFMA flash attention ----------------
// Grid: (T/128, B*H). 256 threads = 4 waves, each wave owns 32 q-rows.
// K staged [64][72] LDS; V comes pre-transposed [B,H,HS,T] -> Vts[64 d][72].
__launch_bounds__(256)
__global__ void attn_mfma(const unsigned short* __restrict__ qw,
                          const unsigned short* __restrict__ kw,
                          const unsigned short* __restrict__ vt,
                          unsigned short* __restrict__ yw) {
    __shared__ unsigned short Ks[64][72];    // +8 pad: 144B rows (16B aligned)
    __shared__ unsigned short Vts[64][72];
    __shared__ unsigned short Ps[4][32][72]; // per-wave P (32 q x 64 kv)
    const int tid = threadIdx.x, lane = tid & 63;
    const int wid = tid >> 6;
    const int cl = lane & 15, gl = lane >> 4;
    const int qt = blockIdx.x;      // 0..15
    const int bh = blockIdx.y;      // 0..63
    const size_t base = (size_t)bh * T_ * HS_;
    const int q0 = qt * 128 + wid * 32;

    // Q fragments in registers: [qm][kh]
    bf16x8 qf[2][2];
    #pragma unroll
    for (int qm = 0; qm < 2; qm++)
        #pragma unroll
        for (int kh = 0; kh < 2; kh++)
            qf[qm][kh] = *(const bf16x8*)&qw[base + (size_t)(q0 + qm * 16 + cl) * HS_ + kh * 32 + 8 * gl];

    f32x4 o_acc[2][4];
    #pragma unroll
    for (int qm = 0; qm < 2; qm++)
        #pragma unroll
        for (int dn = 0; dn < 4; dn++) o_acc[qm][dn] = (f32x4)0.0f;
    float m_[2][4], l_[2][4];
    #pragma unroll
    for (int qm = 0; qm < 2; qm++)
        #pragma unroll
        for (int r = 0; r < 4; r++) { m_[qm][r] = -INFINITY; l_[qm][r] = 0.f; }

    const int ntiles = 2 * qt + 2;
    for (int kt = 0; kt < ntiles; kt++) {
        __syncthreads();
        #pragma unroll
        for (int i = 0; i < 2; i++) {
            int idx = tid + i * 256;           // 0..511
            int row = idx >> 3, c8 = idx & 7;
            *(bf16x8*)&Ks[row][c8 * 8] =
                *(const bf16x8*)&kw[base + (size_t)(kt * 64 + row) * HS_ + c8 * 8];
            *(bf16x8*)&Vts[row][c8 * 8] =
                *(const bf16x8*)&vt[base + (size_t)row * T_ + kt * 64 + c8 * 8];
        }
        __syncthreads();

        // S = Q K^T  (16 MFMAs)
        bf16x8 kf[4][2];
        #pragma unroll
        for (int kn = 0; kn < 4; kn++)
            #pragma unroll
            for (int kh = 0; kh < 2; kh++)
                kf[kn][kh] = *(bf16x8*)&Ks[kn * 16 + cl][kh * 32 + 8 * gl];
        f32x4 s[2][4];
        #pragma unroll
        for (int qm = 0; qm < 2; qm++)
            #pragma unroll
            for (int kn = 0; kn < 4; kn++) {
                f32x4 t0 = (f32x4)0.0f;
                t0 = __builtin_amdgcn_mfma_f32_16x16x32_bf16(qf[qm][0], kf[kn][0], t0, 0, 0, 0);
                s[qm][kn] = __builtin_amdgcn_mfma_f32_16x16x32_bf16(qf[qm][1], kf[kn][1], t0, 0, 0, 0);
            }

        // scale + causal mask + online softmax
        float alpha[2][4];
        #pragma unroll
        for (int qm = 0; qm < 2; qm++) {
            #pragma unroll
            for (int kn = 0; kn < 4; kn++)
                #pragma unroll
                for (int r = 0; r < 4; r++) {
                    int kv = kt * 64 + kn * 16 + cl;
                    int qg = q0 + qm * 16 + 4 * gl + r;
                    float v = s[qm][kn][r] * 0.125f;
                    s[qm][kn][r] = (kv <= qg) ? v : -INFINITY;
                }
            #pragma unroll
            for (int r = 0; r < 4; r++) {
                float mx = fmaxf(fmaxf(s[qm][0][r], s[qm][1][r]),
                                 fmaxf(s[qm][2][r], s[qm][3][r]));
                #pragma unroll
                for (int off = 8; off >= 1; off >>= 1) mx = fmaxf(mx, __shfl_xor(mx, off));
                float nm = fmaxf(m_[qm][r], mx);
                float al = __expf(m_[qm][r] - nm);
                m_[qm][r] = nm;
                alpha[qm][r] = al;
                float ps = 0.f;
                #pragma unroll
                for (int kn = 0; kn < 4; kn++) {
                    float p = __expf(s[qm][kn][r] - nm);
                    s[qm][kn][r] = p;
                    ps += p;
                }
                l_[qm][r] = l_[qm][r] * al + ps;
            }
        }

        // P -> LDS (same-wave, no barrier needed)
        #pragma unroll
        for (int qm = 0; qm < 2; qm++)
            #pragma unroll
            for (int kn = 0; kn < 4; kn++)
                #pragma unroll
                for (int r = 0; r < 4; r++)
                    Ps[wid][qm * 16 + 4 * gl + r][kn * 16 + cl] = f2bf(s[qm][kn][r]);

        // rescale O
        #pragma unroll
        for (int qm = 0; qm < 2; qm++)
            #pragma unroll
            for (int dn = 0; dn < 4; dn++)
                #pragma unroll
                for (int r = 0; r < 4; r++)
                    o_acc[qm][dn][r] *= alpha[qm][r];

        // O += P V   (16 MFMAs)
        bf16x8 pf[2][2], vf[4][2];
        #pragma unroll
        for (int qm = 0; qm < 2; qm++)
            #pragma unroll
            for (int ks = 0; ks < 2; ks++)
                pf[qm][ks] = *(bf16x8*)&Ps[wid][qm * 16 + cl][ks * 32 + 8 * gl];
        #pragma unroll
        for (int dn = 0; dn < 4; dn++)
            #pragma unroll
            for (int ks = 0; ks < 2; ks++)
                vf[dn][ks] = *(bf16x8*)&Vts[dn * 16 + cl][ks * 32 + 8 * gl];
        #pragma unroll
        for (int qm = 0; qm < 2; qm++)
            #pragma unroll
            for (int dn = 0; dn < 4; dn++)
                #pragma unroll
                for (int ks = 0; ks < 2; ks++)
                    o_acc[qm][dn] = __builtin_amdgcn_mfma_f32_16x16x32_bf16(
                        pf[qm][ks], vf[dn][ks], o_acc[qm][dn], 0, 0, 0);
    }

    // final: reduce l across the 16-lane group, normalize, write y [B,T,C]
    const int bq = bh >> 4, h = bh & 15;
    #pragma unroll
    for (int qm = 0; qm < 2; qm++)
        #pragma unroll
        for (int r = 0; r < 4; r++) {
            float l = l_[qm][r];
            #pragma unroll
            for (int off = 8; off >= 1; off >>= 1) l += __shfl_xor(l, off);
            l_[qm][r] = 1.0f / l;
        }
    #pragma unroll
    for (int qm = 0; qm < 2; qm++)
        #pragma unroll
        for (int dn = 0; dn < 4; dn++)
            #pragma unroll
            for (int r = 0; r < 4; r++) {
                int qg = q0 + qm * 16 + 4 * gl + r;
                int d = dn * 16 + cl;
                yw[((size_t)(bq * T_ + qg)) * C_ + h * HS_ + d] =
                    f2bf(o_acc[qm][dn][r] * l_[qm][r]);
            }
}

// ---------------- Output projection: y[8192,1024] @ w_proj[1024,1024] + b ----------------
__launch_bounds__(256)
__global__ void proj_gemm(const unsigned short* __restrict__ y, const float* __restrict__ w,
                          const float* __restrict__ bias, float* __restrict__ out) {
    const int N = C_, K = C_;
    __shared__ unsigned short As[128][40];
    __shared__ unsigned short Bs[64][40];
    const int tid = threadIdx.x;
    const int lane = tid & 63;
    const int wid = tid >> 6;
    const int waveM = wid >> 1, waveN = wid & 1;
    const int m0 = blockIdx.y * 128;
    const int n0 = blockIdx.x * 64;

    f32x4 acc[4][2];
    #pragma unroll
    for (int i = 0; i < 4; i++)
        #pragma unroll
        for (int j = 0; j < 2; j++) acc[i][j] = (f32x4)0.0f;

    for (int kk = 0; kk < K; kk += 32) {
        #pragma unroll
        for (int i = 0; i < 4; i++) {
            int idx = tid + i * 256;
            int row = idx >> 3, c4 = idx & 7;
            *(ushort4*)&As[row][c4 * 4] = *(const ushort4*)&y[(size_t)(m0 + row) * K + kk + c4 * 4];
        }
        #pragma unroll
        for (int i = 0; i < 2; i++) {
            int idx = tid + i * 256;
            int n = idx & 63, k4 = idx >> 6;
            ushort4 o;
            o.x = f2bf(w[(size_t)(kk + k4 * 4 + 0) * N + n0 + n]);
            o.y = f2bf(w[(size_t)(kk + k4 * 4 + 1) * N + n0 + n]);
            o.z = f2bf(w[(size_t)(kk + k4 * 4 + 2) * N + n0 + n]);
            o.w = f2bf(w[(size_t)(kk + k4 * 4 + 3) * N + n0 + n]);
            *(ushort4*)&Bs[n][k4 * 4] = o;
        }
        __syncthreads();
        bf16x8 a[4], b[2];
        #pragma unroll
        for (int mf = 0; mf < 4; mf++)
            a[mf] = *(bf16x8*)&As[waveM * 64 + mf * 16 + (lane & 15)][8 * (lane >> 4)];
        #pragma unroll
        for (int nf = 0; nf < 2; nf++)
            b[nf] = *(bf16x8*)&Bs[waveN * 32 + nf * 16 + (lane & 15)][8 * (lane >> 4)];
        #pragma unroll
        for (int mf = 0; mf < 4; mf++)
            #pragma unroll
            for (int nf = 0; nf < 2; nf++)
                acc[mf][nf] = __builtin_amdgcn_mfma_f32_16x16x32_bf16(a[mf], b[nf], acc[mf][nf], 0, 0, 0);
        __syncthreads();
    }
    #pragma unroll
    for (int mf = 0; mf < 4; mf++)
        #pragma unroll
        for (int nf = 0; nf < 2; nf++)
            #pragma unroll
            for (int r = 0; r < 4; r++) {
                int rg = m0 + waveM * 64 + mf * 16 + (lane >> 4) * 4 + r;
                int cg = n0 + waveN * 32 + nf * 16 + (lane & 15);
                out[(size_t)rg * N + cg] = acc[mf][nf][r] + bias[cg];
            }
}

extern "C" void kernel_launch(void* const* d_in, const int* in_sizes, int n_in,
                              void* d_out, int out_size, void* d_ws, size_t ws_size,
                              hipStream_t stream) {
    const float* x      = (const float*)d_in[0];
    const float* w_attn = (const float*)d_in[1];
    const float* b_attn = (const float*)d_in[2];
    const float* w_proj = (const float*)d_in[3];
    const float* b_proj = (const float*)d_in[4];
    float* out = (float*)d_out;

    unsigned short* qw = (unsigned short*)d_ws;
    const size_t E = (size_t)M_ * C_;   // 8388608
    unsigned short* kw = qw + E;
    unsigned short* vt = kw + E;        // [B,H,HS,T]
    unsigned short* yw = vt + E;        // [B,T,C]

    qkv_gemm<<<dim3(48, 64), 256, 0, stream>>>(x, w_attn, b_attn, qw, kw, vt);
    attn_mfma<<<dim3(16, 64), 256, 0, stream>>>(qw, kw, vt, yw);
    proj_gemm<<<dim3(16, 64), 256, 0, stream>>>(yw, w_proj, b_proj, out);
}

// Round 4
// 332.312 us; speedup vs baseline: 6.0672x; 1.6429x over previous
//
#include <hip/hip_runtime.h>
#include <hip/hip_bf16.h>

// Problem: B=4, T=2048, C=1024, H=16, HS=64. M = B*T = 8192.
#define B_ 4
#define T_ 2048
#define C_ 1024
#define H_ 16
#define HS_ 64
#define M_ (B_*T_)

typedef __bf16 bf16_t;
typedef bf16_t bf16x8 __attribute__((ext_vector_type(8)));
typedef float f32x4 __attribute__((ext_vector_type(4)));
typedef unsigned short ushort_t;

__device__ __forceinline__ unsigned short f2bf(float f) {
    __hip_bfloat16 h = __float2bfloat16(f);
    return __builtin_bit_cast(unsigned short, h);
}

__device__ __forceinline__ void glds16(const void* g, void* l) {
    __builtin_amdgcn_global_load_lds((const __attribute__((address_space(1))) void*)g,
                                     (__attribute__((address_space(3))) void*)l, 16, 0, 0);
}

// ---------------- prep: x fp32 -> bf16 row-major ----------------
__launch_bounds__(256)
__global__ void cvt_x(const float* __restrict__ in, ushort_t* __restrict__ out) {
    int i = blockIdx.x * 256 + threadIdx.x;   // 8 elems per thread
    const float4* p = (const float4*)in;
    float4 a = p[i * 2], b = p[i * 2 + 1];
    ushort4 o0, o1;
    o0.x = f2bf(a.x); o0.y = f2bf(a.y); o0.z = f2bf(a.z); o0.w = f2bf(a.w);
    o1.x = f2bf(b.x); o1.y = f2bf(b.y); o1.z = f2bf(b.z); o1.w = f2bf(b.w);
    *(ushort4*)&out[i * 8] = o0;
    *(ushort4*)&out[i * 8 + 4] = o1;
}

// ---------------- prep: w [K][N] fp32 -> wT [N][K] bf16 (64x64 LDS tiles) ----------------
__launch_bounds__(256)
__global__ void transpose_cvt(const float* __restrict__ w, ushort_t* __restrict__ wT,
                              int K, int N) {
    __shared__ ushort_t Ts[64][72];
    const int n0 = blockIdx.x * 64, k0 = blockIdx.y * 64;
    const int t = threadIdx.x, r = t >> 2, cq = t & 3;
    #pragma unroll
    for (int j = 0; j < 4; j++) {
        float4 v = *(const float4*)&w[(size_t)(k0 + r) * N + n0 + cq * 16 + j * 4];
        ushort4 o;
        o.x = f2bf(v.x); o.y = f2bf(v.y); o.z = f2bf(v.z); o.w = f2bf(v.w);
        *(ushort4*)&Ts[r][cq * 16 + j * 4] = o;
    }
    __syncthreads();
    #pragma unroll
    for (int j = 0; j < 4; j++) {
        ushort4 o;
        o.x = Ts[cq * 16 + j * 4 + 0][r];
        o.y = Ts[cq * 16 + j * 4 + 1][r];
        o.z = Ts[cq * 16 + j * 4 + 2][r];
        o.w = Ts[cq * 16 + j * 4 + 3][r];
        *(ushort4*)&wT[(size_t)(n0 + r) * K + k0 + cq * 16 + j * 4] = o;
    }
}

// ---------------- QKV GEMM (m97 structure): xb[8192,1024] @ watT[3072,1024]^T ----------------
// 128x128 tile, BK=32, 4 waves (2x2), each wave 64x64 (4x4 frags), global_load_lds w16.
// Q,K -> [B,H,T,HS]; V -> transposed [B,H,HS,T].
__launch_bounds__(256)
__global__ void qkv_gemm(const ushort_t* __restrict__ xb, const ushort_t* __restrict__ wT,
                         const float* __restrict__ bias,
                         ushort_t* __restrict__ qw, ushort_t* __restrict__ kw,
                         ushort_t* __restrict__ vt) {
    const int K = C_;
    __shared__ ushort_t As[128 * 32];
    __shared__ ushort_t Bs[128 * 32];
    const int tid = threadIdx.x, lane = tid & 63, wid = tid >> 6;
    const int cl = lane & 15, gl = lane >> 4;
    const int waveM = wid >> 1, waveN = wid & 1;
    const int m0 = blockIdx.y * 128, n0 = blockIdx.x * 128;
    const int srow = tid >> 2, scq = tid & 3;   // staging: 16B chunk per (row, quarter)

    f32x4 acc[4][4];
    #pragma unroll
    for (int mf = 0; mf < 4; mf++)
        #pragma unroll
        for (int nf = 0; nf < 4; nf++) acc[mf][nf] = (f32x4)0.0f;

    for (int kk = 0; kk < K; kk += 32) {
        #pragma unroll
        for (int i = 0; i < 2; i++) {
            int c = tid + i * 256;            // chunk 0..511
            int row = srow + i * 64;
            glds16(&xb[(size_t)(m0 + row) * K + kk + scq * 8], &As[(size_t)c * 8]);
            glds16(&wT[(size_t)(n0 + row) * K + kk + scq * 8], &Bs[(size_t)c * 8]);
        }
        __syncthreads();
        bf16x8 a[4], b[4];
        #pragma unroll
        for (int mf = 0; mf < 4; mf++)
            a[mf] = *(bf16x8*)&As[(waveM * 64 + mf * 16 + cl) * 32 + gl * 8];
        #pragma unroll
        for (int nf = 0; nf < 4; nf++)
            b[nf] = *(bf16x8*)&Bs[(waveN * 64 + nf * 16 + cl) * 32 + gl * 8];
        #pragma unroll
        for (int mf = 0; mf < 4; mf++)
            #pragma unroll
            for (int nf = 0; nf < 4; nf++)
                acc[mf][nf] = __builtin_amdgcn_mfma_f32_16x16x32_bf16(a[mf], b[nf], acc[mf][nf], 0, 0, 0);
        __syncthreads();
    }
    const int secb = n0 >> 10;                // uniform per block (128 | 1024)
    #pragma unroll
    for (int mf = 0; mf < 4; mf++)
        #pragma unroll
        for (int nf = 0; nf < 4; nf++)
            #pragma unroll
            for (int r = 0; r < 4; r++) {
                int rg = m0 + waveM * 64 + mf * 16 + 4 * gl + r;
                int cg = n0 + waveN * 64 + nf * 16 + cl;
                float val = acc[mf][nf][r] + bias[cg];
                int cc = cg & 1023;
                int h = cc >> 6, hs = cc & 63;
                int bb = rg >> 11, tq = rg & 2047;
                if (secb == 0)
                    qw[(((size_t)(bb * H_ + h)) * T_ + tq) * HS_ + hs] = f2bf(val);
                else if (secb == 1)
                    kw[(((size_t)(bb * H_ + h)) * T_ + tq) * HS_ + hs] = f2bf(val);
                else
                    vt[(((size_t)(bb * H_ + h)) * HS_ + hs) * T_ + tq] = f2bf(val);
            }
}

// ---------------- MFMA flash attention, qt-paired + async-STAGE ----------------
// Grid (8, 64): block handles q-tiles {qp, 15-qp} (34 kv-tiles uniform).
__launch_bounds__(256, 2)
__global__ void attn_mfma(const ushort_t* __restrict__ qw,
                          const ushort_t* __restrict__ kw,
                          const ushort_t* __restrict__ vt,
                          ushort_t* __restrict__ yw) {
    __shared__ ushort_t Ks[64][72];
    __shared__ ushort_t Vts[64][72];
    __shared__ ushort_t Ps[4][32][72];
    const int tid = threadIdx.x, lane = tid & 63, wid = tid >> 6;
    const int cl = lane & 15, gl = lane >> 4;
    const int qp = blockIdx.x;            // 0..7
    const int bh = blockIdx.y;            // 0..63
    const size_t base = (size_t)bh * T_ * HS_;
    const int bq = bh >> 4, h = bh & 15;
    const int srow = tid >> 3, scq = tid & 7;   // staging row (0..31 +32i), chunk (0..7)

    for (int half = 0; half < 2; half++) {
        const int qt = half ? (15 - qp) : qp;
        const int q0 = qt * 128 + wid * 32;
        const int ntiles = 2 * qt + 2;

        bf16x8 qf[2][2];
        #pragma unroll
        for (int qm = 0; qm < 2; qm++)
            #pragma unroll
            for (int kh = 0; kh < 2; kh++)
                qf[qm][kh] = *(const bf16x8*)&qw[base + (size_t)(q0 + qm * 16 + cl) * HS_ + kh * 32 + 8 * gl];

        f32x4 o_acc[2][4];
        #pragma unroll
        for (int qm = 0; qm < 2; qm++)
            #pragma unroll
            for (int dn = 0; dn < 4; dn++) o_acc[qm][dn] = (f32x4)0.0f;
        float m_[2][4], l_[2][4];
        #pragma unroll
        for (int qm = 0; qm < 2; qm++)
            #pragma unroll
            for (int r = 0; r < 4; r++) { m_[qm][r] = -INFINITY; l_[qm][r] = 0.f; }

        // prologue: prefetch tile 0 into registers
        bf16x8 kpre[2], vpre[2], knew[2], vnew[2];
        #pragma unroll
        for (int i = 0; i < 2; i++) {
            int row = srow + i * 32;
            kpre[i] = *(const bf16x8*)&kw[base + (size_t)row * HS_ + scq * 8];
            vpre[i] = *(const bf16x8*)&vt[base + (size_t)row * T_ + scq * 8];
        }

        for (int kt = 0; kt < ntiles; kt++) {
            __syncthreads();   // prior tile's LDS reads complete
            // issue next tile's loads first (max in-flight under compute)
            if (kt + 1 < ntiles) {
                #pragma unroll
                for (int i = 0; i < 2; i++) {
                    int row = srow + i * 32;
                    knew[i] = *(const bf16x8*)&kw[base + (size_t)((kt + 1) * 64 + row) * HS_ + scq * 8];
                    vnew[i] = *(const bf16x8*)&vt[base + (size_t)row * T_ + (kt + 1) * 64 + scq * 8];
                }
            }
            // write current tile to LDS (regs loaded during previous compute)
            #pragma unroll
            for (int i = 0; i < 2; i++) {
                int row = srow + i * 32;
                *(bf16x8*)&Ks[row][scq * 8] = kpre[i];
                *(bf16x8*)&Vts[row][scq * 8] = vpre[i];
            }
            __syncthreads();

            // S = Q K^T
            bf16x8 kf[4][2];
            #pragma unroll
            for (int kn = 0; kn < 4; kn++)
                #pragma unroll
                for (int kh = 0; kh < 2; kh++)
                    kf[kn][kh] = *(bf16x8*)&Ks[kn * 16 + cl][kh * 32 + 8 * gl];
            f32x4 s[2][4];
            #pragma unroll
            for (int qm = 0; qm < 2; qm++)
                #pragma unroll
                for (int kn = 0; kn < 4; kn++) {
                    f32x4 t0 = (f32x4)0.0f;
                    t0 = __builtin_amdgcn_mfma_f32_16x16x32_bf16(qf[qm][0], kf[kn][0], t0, 0, 0, 0);
                    s[qm][kn] = __builtin_amdgcn_mfma_f32_16x16x32_bf16(qf[qm][1], kf[kn][1], t0, 0, 0, 0);
                }

            // scale + mask + online softmax
            float alpha[2][4];
            #pragma unroll
            for (int qm = 0; qm < 2; qm++) {
                #pragma unroll
                for (int kn = 0; kn < 4; kn++)
                    #pragma unroll
                    for (int r = 0; r < 4; r++) {
                        int kv = kt * 64 + kn * 16 + cl;
                        int qg = q0 + qm * 16 + 4 * gl + r;
                        float v = s[qm][kn][r] * 0.125f;
                        s[qm][kn][r] = (kv <= qg) ? v : -INFINITY;
                    }
                #pragma unroll
                for (int r = 0; r < 4; r++) {
                    float mx = fmaxf(fmaxf(s[qm][0][r], s[qm][1][r]),
                                     fmaxf(s[qm][2][r], s[qm][3][r]));
                    #pragma unroll
                    for (int off = 8; off >= 1; off >>= 1) mx = fmaxf(mx, __shfl_xor(mx, off));
                    float nm = fmaxf(m_[qm][r], mx);
                    float al = __expf(m_[qm][r] - nm);
                    m_[qm][r] = nm;
                    alpha[qm][r] = al;
                    float ps = 0.f;
                    #pragma unroll
                    for (int kn = 0; kn < 4; kn++) {
                        float p = __expf(s[qm][kn][r] - nm);
                        s[qm][kn][r] = p;
                        ps += p;
                    }
                    l_[qm][r] = l_[qm][r] * al + ps;
                }
            }

            // P -> LDS (same-wave)
            #pragma unroll
            for (int qm = 0; qm < 2; qm++)
                #pragma unroll
                for (int kn = 0; kn < 4; kn++)
                    #pragma unroll
                    for (int r = 0; r < 4; r++)
                        Ps[wid][qm * 16 + 4 * gl + r][kn * 16 + cl] = f2bf(s[qm][kn][r]);

            // rescale O
            #pragma unroll
            for (int qm = 0; qm < 2; qm++)
                #pragma unroll
                for (int dn = 0; dn < 4; dn++)
                    #pragma unroll
                    for (int r = 0; r < 4; r++)
                        o_acc[qm][dn][r] *= alpha[qm][r];

            // O += P V
            bf16x8 pf[2][2], vf[4][2];
            #pragma unroll
            for (int qm = 0; qm < 2; qm++)
                #pragma unroll
                for (int ks = 0; ks < 2; ks++)
                    pf[qm][ks] = *(bf16x8*)&Ps[wid][qm * 16 + cl][ks * 32 + 8 * gl];
            #pragma unroll
            for (int dn = 0; dn < 4; dn++)
                #pragma unroll
                for (int ks = 0; ks < 2; ks++)
                    vf[dn][ks] = *(bf16x8*)&Vts[dn * 16 + cl][ks * 32 + 8 * gl];
            #pragma unroll
            for (int qm = 0; qm < 2; qm++)
                #pragma unroll
                for (int dn = 0; dn < 4; dn++)
                    #pragma unroll
                    for (int ks = 0; ks < 2; ks++)
                        o_acc[qm][dn] = __builtin_amdgcn_mfma_f32_16x16x32_bf16(
                            pf[qm][ks], vf[dn][ks], o_acc[qm][dn], 0, 0, 0);

            #pragma unroll
            for (int i = 0; i < 2; i++) { kpre[i] = knew[i]; vpre[i] = vnew[i]; }
        }

        // reduce l, normalize, write y [B,T,C]
        #pragma unroll
        for (int qm = 0; qm < 2; qm++)
            #pragma unroll
            for (int r = 0; r < 4; r++) {
                float l = l_[qm][r];
                #pragma unroll
                for (int off = 8; off >= 1; off >>= 1) l += __shfl_xor(l, off);
                l_[qm][r] = 1.0f / l;
            }
        #pragma unroll
        for (int qm = 0; qm < 2; qm++)
            #pragma unroll
            for (int dn = 0; dn < 4; dn++)
                #pragma unroll
                for (int r = 0; r < 4; r++) {
                    int qg = q0 + qm * 16 + 4 * gl + r;
                    int d = dn * 16 + cl;
                    yw[((size_t)(bq * T_ + qg)) * C_ + h * HS_ + d] =
                        f2bf(o_acc[qm][dn][r] * l_[qm][r]);
                }
    }
}

// ---------------- Output projection (m97 structure): y[8192,1024] @ wpT[1024,1024]^T ----------------
__launch_bounds__(256)
__global__ void proj_gemm(const ushort_t* __restrict__ y, const ushort_t* __restrict__ wT,
                          const float* __restrict__ bias, float* __restrict__ out) {
    const int K = C_, N = C_;
    __shared__ ushort_t As[128 * 32];
    __shared__ ushort_t Bs[128 * 32];
    const int tid = threadIdx.x, lane = tid & 63, wid = tid >> 6;
    const int cl = lane & 15, gl = lane >> 4;
    const int waveM = wid >> 1, waveN = wid & 1;
    const int m0 = blockIdx.y * 128, n0 = blockIdx.x * 128;
    const int srow = tid >> 2, scq = tid & 3;

    f32x4 acc[4][4];
    #pragma unroll
    for (int mf = 0; mf < 4; mf++)
        #pragma unroll
        for (int nf = 0; nf < 4; nf++) acc[mf][nf] = (f32x4)0.0f;

    for (int kk = 0; kk < K; kk += 32) {
        #pragma unroll
        for (int i = 0; i < 2; i++) {
            int c = tid + i * 256;
            int row = srow + i * 64;
            glds16(&y[(size_t)(m0 + row) * K + kk + scq * 8], &As[(size_t)c * 8]);
            glds16(&wT[(size_t)(n0 + row) * K + kk + scq * 8], &Bs[(size_t)c * 8]);
        }
        __syncthreads();
        bf16x8 a[4], b[4];
        #pragma unroll
        for (int mf = 0; mf < 4; mf++)
            a[mf] = *(bf16x8*)&As[(waveM * 64 + mf * 16 + cl) * 32 + gl * 8];
        #pragma unroll
        for (int nf = 0; nf < 4; nf++)
            b[nf] = *(bf16x8*)&Bs[(waveN * 64 + nf * 16 + cl) * 32 + gl * 8];
        #pragma unroll
        for (int mf = 0; mf < 4; mf++)
            #pragma unroll
            for (int nf = 0; nf < 4; nf++)
                acc[mf][nf] = __builtin_amdgcn_mfma_f32_16x16x32_bf16(a[mf], b[nf], acc[mf][nf], 0, 0, 0);
        __syncthreads();
    }
    #pragma unroll
    for (int mf = 0; mf < 4; mf++)
        #pragma unroll
        for (int nf = 0; nf < 4; nf++)
            #pragma unroll
            for (int r = 0; r < 4; r++) {
                int rg = m0 + waveM * 64 + mf * 16 + 4 * gl + r;
                int cg = n0 + waveN * 64 + nf * 16 + cl;
                out[(size_t)rg * N + cg] = acc[mf][nf][r] + bias[cg];
            }
}

extern "C" void kernel_launch(void* const* d_in, const int* in_sizes, int n_in,
                              void* d_out, int out_size, void* d_ws, size_t ws_size,
                              hipStream_t stream) {
    const float* x      = (const float*)d_in[0];
    const float* w_attn = (const float*)d_in[1];
    const float* b_attn = (const float*)d_in[2];
    const float* w_proj = (const float*)d_in[3];
    const float* b_proj = (const float*)d_in[4];
    float* out = (float*)d_out;

    const size_t E = (size_t)M_ * C_;   // 8388608
    ushort_t* qw  = (ushort_t*)d_ws;
    ushort_t* kw  = qw + E;
    ushort_t* vt  = kw + E;             // [B,H,HS,T]
    ushort_t* xy  = vt + E;             // xb during qkv, then yw [B,T,C]
    ushort_t* wat = xy + E;             // w_attn^T [3072][1024]
    ushort_t* wpt = vt;                 // w_proj^T reuses vt slot after attn

    cvt_x<<<dim3(4096), 256, 0, stream>>>(x, xy);
    transpose_cvt<<<dim3(48, 16), 256, 0, stream>>>(w_attn, wat, C_, 3 * C_);
    qkv_gemm<<<dim3(24, 64), 256, 0, stream>>>(xy, wat, b_attn, qw, kw, vt);
    attn_mfma<<<dim3(8, 64), 256, 0, stream>>>(qw, kw, vt, xy);
    transpose_cvt<<<dim3(16, 16), 256, 0, stream>>>(w_proj, wpt, C_, C_);
    proj_gemm<<<dim3(8, 64), 256, 0, stream>>>(xy, wpt, b_proj, out);
}

// Round 6
// 295.828 us; speedup vs baseline: 6.8155x; 1.1233x over previous
//
#include <hip/hip_runtime.h>
#include <hip/hip_bf16.h>

// Problem: B=4, T=2048, C=1024, H=16, HS=64. M = B*T = 8192.
#define B_ 4
#define T_ 2048
#define C_ 1024
#define H_ 16
#define HS_ 64
#define M_ (B_*T_)
#define QSCALE 0.18033688011112042f   // 0.125 * log2(e): softmax in exp2 domain

typedef __bf16 bf16_t;
typedef bf16_t bf16x8 __attribute__((ext_vector_type(8)));
typedef float f32x4 __attribute__((ext_vector_type(4)));
typedef unsigned short ushort_t;

__device__ __forceinline__ unsigned short f2bf(float f) {
    __hip_bfloat16 h = __float2bfloat16(f);
    return __builtin_bit_cast(unsigned short, h);
}

__device__ __forceinline__ void glds16(const void* g, void* l) {
    __builtin_amdgcn_global_load_lds((const __attribute__((address_space(1))) void*)g,
                                     (__attribute__((address_space(3))) void*)l, 16, 0, 0);
}

// ---------------- prep: x fp32 -> bf16 row-major ----------------
__launch_bounds__(256)
__global__ void cvt_x(const float* __restrict__ in, ushort_t* __restrict__ out) {
    int i = blockIdx.x * 256 + threadIdx.x;   // 8 elems per thread
    const float4* p = (const float4*)in;
    float4 a = p[i * 2], b = p[i * 2 + 1];
    ushort4 o0, o1;
    o0.x = f2bf(a.x); o0.y = f2bf(a.y); o0.z = f2bf(a.z); o0.w = f2bf(a.w);
    o1.x = f2bf(b.x); o1.y = f2bf(b.y); o1.z = f2bf(b.z); o1.w = f2bf(b.w);
    *(ushort4*)&out[i * 8] = o0;
    *(ushort4*)&out[i * 8 + 4] = o1;
}

// ---------------- prep: w [K][N] fp32 -> wT [N][K] bf16 (64x64 LDS tiles) ----------------
__launch_bounds__(256)
__global__ void transpose_cvt(const float* __restrict__ w, ushort_t* __restrict__ wT,
                              int K, int N) {
    __shared__ ushort_t Ts[64][72];
    const int n0 = blockIdx.x * 64, k0 = blockIdx.y * 64;
    const int t = threadIdx.x, r = t >> 2, cq = t & 3;
    #pragma unroll
    for (int j = 0; j < 4; j++) {
        float4 v = *(const float4*)&w[(size_t)(k0 + r) * N + n0 + cq * 16 + j * 4];
        ushort4 o;
        o.x = f2bf(v.x); o.y = f2bf(v.y); o.z = f2bf(v.z); o.w = f2bf(v.w);
        *(ushort4*)&Ts[r][cq * 16 + j * 4] = o;
    }
    __syncthreads();
    #pragma unroll
    for (int j = 0; j < 4; j++) {
        ushort4 o;
        o.x = Ts[cq * 16 + j * 4 + 0][r];
        o.y = Ts[cq * 16 + j * 4 + 1][r];
        o.z = Ts[cq * 16 + j * 4 + 2][r];
        o.w = Ts[cq * 16 + j * 4 + 3][r];
        *(ushort4*)&wT[(size_t)(n0 + r) * K + k0 + cq * 16 + j * 4] = o;
    }
}

// ---------------- QKV GEMM (m97 structure): xb[8192,1024] @ watT[3072,1024]^T ----------------
// Q -> [B,H,T,HS] PRESCALED by QSCALE; K -> [B,H,T,HS]; V -> transposed [B,H,HS,T].
__launch_bounds__(256)
__global__ void qkv_gemm(const ushort_t* __restrict__ xb, const ushort_t* __restrict__ wT,
                         const float* __restrict__ bias,
                         ushort_t* __restrict__ qw, ushort_t* __restrict__ kw,
                         ushort_t* __restrict__ vt) {
    const int K = C_;
    __shared__ ushort_t As[128 * 32];
    __shared__ ushort_t Bs[128 * 32];
    const int tid = threadIdx.x, lane = tid & 63, wid = tid >> 6;
    const int cl = lane & 15, gl = lane >> 4;
    const int waveM = wid >> 1, waveN = wid & 1;
    const int m0 = blockIdx.y * 128, n0 = blockIdx.x * 128;
    const int srow = tid >> 2, scq = tid & 3;

    f32x4 acc[4][4];
    #pragma unroll
    for (int mf = 0; mf < 4; mf++)
        #pragma unroll
        for (int nf = 0; nf < 4; nf++) acc[mf][nf] = (f32x4)0.0f;

    for (int kk = 0; kk < K; kk += 32) {
        #pragma unroll
        for (int i = 0; i < 2; i++) {
            int c = tid + i * 256;
            int row = srow + i * 64;
            glds16(&xb[(size_t)(m0 + row) * K + kk + scq * 8], &As[(size_t)c * 8]);
            glds16(&wT[(size_t)(n0 + row) * K + kk + scq * 8], &Bs[(size_t)c * 8]);
        }
        __syncthreads();
        bf16x8 a[4], b[4];
        #pragma unroll
        for (int mf = 0; mf < 4; mf++)
            a[mf] = *(bf16x8*)&As[(waveM * 64 + mf * 16 + cl) * 32 + gl * 8];
        #pragma unroll
        for (int nf = 0; nf < 4; nf++)
            b[nf] = *(bf16x8*)&Bs[(waveN * 64 + nf * 16 + cl) * 32 + gl * 8];
        #pragma unroll
        for (int mf = 0; mf < 4; mf++)
            #pragma unroll
            for (int nf = 0; nf < 4; nf++)
                acc[mf][nf] = __builtin_amdgcn_mfma_f32_16x16x32_bf16(a[mf], b[nf], acc[mf][nf], 0, 0, 0);
        __syncthreads();
    }
    const int secb = n0 >> 10;                // uniform per block
    #pragma unroll
    for (int mf = 0; mf < 4; mf++)
        #pragma unroll
        for (int nf = 0; nf < 4; nf++)
            #pragma unroll
            for (int r = 0; r < 4; r++) {
                int rg = m0 + waveM * 64 + mf * 16 + 4 * gl + r;
                int cg = n0 + waveN * 64 + nf * 16 + cl;
                float val = acc[mf][nf][r] + bias[cg];
                int cc = cg & 1023;
                int h = cc >> 6, hs = cc & 63;
                int bb = rg >> 11, tq = rg & 2047;
                if (secb == 0)
                    qw[(((size_t)(bb * H_ + h)) * T_ + tq) * HS_ + hs] = f2bf(val * QSCALE);
                else if (secb == 1)
                    kw[(((size_t)(bb * H_ + h)) * T_ + tq) * HS_ + hs] = f2bf(val);
                else
                    vt[(((size_t)(bb * H_ + h)) * HS_ + hs) * T_ + tq] = f2bf(val);
            }
}

// ---------------- MFMA flash attention v2 ----------------
// Grid (8, 64), 512 threads = 8 waves, each wave owns 16 q-rows; qt-pairing {qp, 15-qp}.
// Swapped QK^T: st = mfma(K,Q) -> lane holds 4 consecutive kv for q=cl (row-local softmax).
__launch_bounds__(512, 4)
__global__ void attn_mfma(const ushort_t* __restrict__ qw,
                          const ushort_t* __restrict__ kw,
                          const ushort_t* __restrict__ vt,
                          ushort_t* __restrict__ yw) {
    __shared__ ushort_t Ks[64][72];          // 144B rows: b128-aligned, conflict-min
    __shared__ ushort_t Vts[64][72];
    __shared__ ushort_t Ps[8][16][72];       // per-wave P^ (16 q x 64 kv)
    const int tid = threadIdx.x, lane = tid & 63, wid = tid >> 6;
    const int cl = lane & 15, gl = lane >> 4;
    const int qp = blockIdx.x;               // 0..7
    const int bh = blockIdx.y;               // 0..63
    const size_t base = (size_t)bh * T_ * HS_;
    const int bq = bh >> 4, h = bh & 15;
    const int srow = tid >> 3, scq = tid & 7;    // staging: row 0..63, 16B chunk 0..7

    for (int half = 0; half < 2; half++) {
        const int qt = half ? (15 - qp) : qp;
        const int q0 = qt * 128 + wid * 16;      // wave's first q row
        const int ntiles = 2 * qt + 2;

        // Q fragments (B-operand): [kh], row=cl -> q, k=8gl+j (Q prescaled by QSCALE)
        bf16x8 qf[2];
        #pragma unroll
        for (int kh = 0; kh < 2; kh++)
            qf[kh] = *(const bf16x8*)&qw[base + (size_t)(q0 + cl) * HS_ + kh * 32 + 8 * gl];

        f32x4 o_acc[4];
        #pragma unroll
        for (int dn = 0; dn < 4; dn++) o_acc[dn] = (f32x4)0.0f;
        float m_ = -INFINITY, l_ = 0.f;          // row q=q0+cl (replicated over gl); l_ partial per lane

        // prologue prefetch (tile 0)
        bf16x8 kpre, vpre, knew, vnew;
        kpre = *(const bf16x8*)&kw[base + (size_t)srow * HS_ + scq * 8];
        vpre = *(const bf16x8*)&vt[base + (size_t)srow * T_ + scq * 8];

        for (int kt = 0; kt < ntiles; kt++) {
            __syncthreads();
            if (kt + 1 < ntiles) {   // issue next tile's loads early (hide under compute)
                knew = *(const bf16x8*)&kw[base + (size_t)((kt + 1) * 64 + srow) * HS_ + scq * 8];
                vnew = *(const bf16x8*)&vt[base + (size_t)srow * T_ + (kt + 1) * 64 + scq * 8];
            }
            *(bf16x8*)&Ks[srow][scq * 8] = kpre;
            *(bf16x8*)&Vts[srow][scq * 8] = vpre;
            __syncthreads();

            if (kt * 64 <= q0 + 15) {            // not fully masked for this wave
                const bool full = (kt * 64 + 63 <= q0);

                // S^T = K Q^T : lane holds P[kv=kn*16+4gl+r][q=cl]
                f32x4 st[4];
                #pragma unroll
                for (int kn = 0; kn < 4; kn++) {
                    bf16x8 kf0 = *(bf16x8*)&Ks[kn * 16 + cl][8 * gl];
                    bf16x8 kf1 = *(bf16x8*)&Ks[kn * 16 + cl][32 + 8 * gl];
                    f32x4 t0 = (f32x4)0.0f;
                    t0 = __builtin_amdgcn_mfma_f32_16x16x32_bf16(kf0, qf[0], t0, 0, 0, 0);
                    st[kn] = __builtin_amdgcn_mfma_f32_16x16x32_bf16(kf1, qf[1], t0, 0, 0, 0);
                }
                if (!full) {
                    const int qg = q0 + cl;
                    #pragma unroll
                    for (int kn = 0; kn < 4; kn++)
                        #pragma unroll
                        for (int r = 0; r < 4; r++) {
                            int kv = kt * 64 + kn * 16 + 4 * gl + r;
                            if (kv > qg) st[kn][r] = -INFINITY;
                        }
                }

                // row max: 15 in-reg + 2 shuffles
                float mx = st[0][0];
                #pragma unroll
                for (int kn = 0; kn < 4; kn++)
                    #pragma unroll
                    for (int r = 0; r < 4; r++) mx = fmaxf(mx, st[kn][r]);
                mx = fmaxf(mx, __shfl_xor(mx, 16));
                mx = fmaxf(mx, __shfl_xor(mx, 32));
                float nm = fmaxf(m_, mx);
                float nmu = (nm > -INFINITY) ? nm : 0.0f;
                float al = exp2f(m_ - nmu);      // m_=-inf -> 0
                m_ = nm;

                // P = exp2(S - m), partial row-sum per lane, pack to bf16 pairs
                float ps = 0.f;
                #pragma unroll
                for (int kn = 0; kn < 4; kn++) {
                    float p0 = exp2f(st[kn][0] - nmu);
                    float p1 = exp2f(st[kn][1] - nmu);
                    float p2 = exp2f(st[kn][2] - nmu);
                    float p3 = exp2f(st[kn][3] - nmu);
                    ps += (p0 + p1) + (p2 + p3);
                    unsigned lo, hi;
                    asm("v_cvt_pk_bf16_f32 %0, %1, %2" : "=v"(lo) : "v"(p0), "v"(p1));
                    asm("v_cvt_pk_bf16_f32 %0, %1, %2" : "=v"(hi) : "v"(p2), "v"(p3));
                    uint2 wv; wv.x = lo; wv.y = hi;
                    *(uint2*)&Ps[wid][cl][kn * 16 + 4 * gl] = wv;    // ds_write_b64
                }
                l_ = l_ * al + ps;

                // rescale O: alpha for row 4gl+r via broadcast shuffle
                #pragma unroll
                for (int r = 0; r < 4; r++) {
                    float ag = __shfl(al, 4 * gl + r);
                    #pragma unroll
                    for (int dn = 0; dn < 4; dn++) o_acc[dn][r] *= ag;
                }

                // O += P V (A=P row=cl->q, k->kv; B=V^T row=cl->d)
                bf16x8 pf0 = *(bf16x8*)&Ps[wid][cl][8 * gl];
                bf16x8 pf1 = *(bf16x8*)&Ps[wid][cl][32 + 8 * gl];
                #pragma unroll
                for (int dn = 0; dn < 4; dn++) {
                    bf16x8 vf0 = *(bf16x8*)&Vts[dn * 16 + cl][8 * gl];
                    bf16x8 vf1 = *(bf16x8*)&Vts[dn * 16 + cl][32 + 8 * gl];
                    o_acc[dn] = __builtin_amdgcn_mfma_f32_16x16x32_bf16(pf0, vf0, o_acc[dn], 0, 0, 0);
                    o_acc[dn] = __builtin_amdgcn_mfma_f32_16x16x32_bf16(pf1, vf1, o_acc[dn], 0, 0, 0);
                }
            }
            if (kt + 1 < ntiles) { kpre = knew; vpre = vnew; }
        }

        // total l over gl lanes, normalize, write y [B,T,C]
        float ls = l_;
        ls += __shfl_xor(ls, 16);
        ls += __shfl_xor(ls, 32);
        float linv = 1.0f / ls;
        #pragma unroll
        for (int r = 0; r < 4; r++) {
            float lr = __shfl(linv, 4 * gl + r);
            int qg = q0 + 4 * gl + r;
            #pragma unroll
            for (int dn = 0; dn < 4; dn++) {
                int d = dn * 16 + cl;
                yw[((size_t)(bq * T_ + qg)) * C_ + h * HS_ + d] = f2bf(o_acc[dn][r] * lr);
            }
        }
    }
}

// ---------------- Output projection (m97 structure): y[8192,1024] @ wpT[1024,1024]^T ----------------
__launch_bounds__(256)
__global__ void proj_gemm(const ushort_t* __restrict__ y, const ushort_t* __restrict__ wT,
                          const float* __restrict__ bias, float* __restrict__ out) {
    const int K = C_, N = C_;
    __shared__ ushort_t As[128 * 32];
    __shared__ ushort_t Bs[128 * 32];
    const int tid = threadIdx.x, lane = tid & 63, wid = tid >> 6;
    const int cl = lane & 15, gl = lane >> 4;
    const int waveM = wid >> 1, waveN = wid & 1;
    const int m0 = blockIdx.y * 128, n0 = blockIdx.x * 128;
    const int srow = tid >> 2, scq = tid & 3;

    f32x4 acc[4][4];
    #pragma unroll
    for (int mf = 0; mf < 4; mf++)
        #pragma unroll
        for (int nf = 0; nf < 4; nf++) acc[mf][nf] = (f32x4)0.0f;

    for (int kk = 0; kk < K; kk += 32) {
        #pragma unroll
        for (int i = 0; i < 2; i++) {
            int c = tid + i * 256;
            int row = srow + i * 64;
            glds16(&y[(size_t)(m0 + row) * K + kk + scq * 8], &As[(size_t)c * 8]);
            glds16(&wT[(size_t)(n0 + row) * K + kk + scq * 8], &Bs[(size_t)c * 8]);
        }
        __syncthreads();
        bf16x8 a[4], b[4];
        #pragma unroll
        for (int mf = 0; mf < 4; mf++)
            a[mf] = *(bf16x8*)&As[(waveM * 64 + mf * 16 + cl) * 32 + gl * 8];
        #pragma unroll
        for (int nf = 0; nf < 4; nf++)
            b[nf] = *(bf16x8*)&Bs[(waveN * 64 + nf * 16 + cl) * 32 + gl * 8];
        #pragma unroll
        for (int mf = 0; mf < 4; mf++)
            #pragma unroll
            for (int nf = 0; nf < 4; nf++)
                acc[mf][nf] = __builtin_amdgcn_mfma_f32_16x16x32_bf16(a[mf], b[nf], acc[mf][nf], 0, 0, 0);
        __syncthreads();
    }
    #pragma unroll
    for (int mf = 0; mf < 4; mf++)
        #pragma unroll
        for (int nf = 0; nf < 4; nf++)
            #pragma unroll
            for (int r = 0; r < 4; r++) {
                int rg = m0 + waveM * 64 + mf * 16 + 4 * gl + r;
                int cg = n0 + waveN * 64 + nf * 16 + cl;
                out[(size_t)rg * N + cg] = acc[mf][nf][r] + bias[cg];
            }
}

extern "C" void kernel_launch(void* const* d_in, const int* in_sizes, int n_in,
                              void* d_out, int out_size, void* d_ws, size_t ws_size,
                              hipStream_t stream) {
    const float* x      = (const float*)d_in[0];
    const float* w_attn = (const float*)d_in[1];
    const float* b_attn = (const float*)d_in[2];
    const float* w_proj = (const float*)d_in[3];
    const float* b_proj = (const float*)d_in[4];
    float* out = (float*)d_out;

    const size_t E = (size_t)M_ * C_;   // 8388608
    ushort_t* qw  = (ushort_t*)d_ws;
    ushort_t* kw  = qw + E;
    ushort_t* vt  = kw + E;             // [B,H,HS,T]
    ushort_t* xy  = vt + E;             // xb during qkv, then yw [B,T,C]
    ushort_t* wat = xy + E;             // w_attn^T [3072][1024]
    ushort_t* wpt = vt;                 // w_proj^T reuses vt slot after attn

    cvt_x<<<dim3(4096), 256, 0, stream>>>(x, xy);
    transpose_cvt<<<dim3(48, 16), 256, 0, stream>>>(w_attn, wat, C_, 3 * C_);
    qkv_gemm<<<dim3(24, 64), 256, 0, stream>>>(xy, wat, b_attn, qw, kw, vt);
    attn_mfma<<<dim3(8, 64), 512, 0, stream>>>(qw, kw, vt, xy);
    transpose_cvt<<<dim3(16, 16), 256, 0, stream>>>(w_proj, wpt, C_, C_);
    proj_gemm<<<dim3(8, 64), 256, 0, stream>>>(xy, wpt, b_proj, out);
}